// Round 1
// baseline (672.476 us; speedup 1.0000x reference)
//
#include <hip/hip_runtime.h>

// CommAttention: B=256, NB=16, HID=512, NH=8, KD=64.
// R3: depth-2 register prefetch pipeline in qkv_gemm and out_gemm
// (issue global loads for tile t+2 while computing tile t; cvt+ds_write
// between barriers). As padded [256][40] to kill 8-way bank conflicts on
// b128 A-fragment reads. Attn / cvt / reduce unchanged from R2.

typedef short s16x4 __attribute__((ext_vector_type(4)));
typedef short s16x8 __attribute__((ext_vector_type(8)));
typedef float f32x4 __attribute__((ext_vector_type(4)));

__device__ __forceinline__ unsigned short f2bf(float f) {
  unsigned int u = __builtin_bit_cast(unsigned int, f);
  u += 0x7fffu + ((u >> 16) & 1u);   // round-to-nearest-even
  return (unsigned short)(u >> 16);
}
__device__ __forceinline__ float bf2f(unsigned short s) {
  unsigned int u = ((unsigned int)s) << 16;
  return __builtin_bit_cast(float, u);
}

// ---------------------------------------------------------------------------
// Prologue: h (2M fp32) -> bf16. grid 2048 x 256.
// ---------------------------------------------------------------------------
__global__ __launch_bounds__(256) void cvt_h(const float* __restrict__ h,
                                             unsigned short* __restrict__ hb)
{
  int i = (blockIdx.x * 256 + threadIdx.x) * 4;
  float4 v = *reinterpret_cast<const float4*>(h + i);
  s16x4 st = { (short)f2bf(v.x), (short)f2bf(v.y), (short)f2bf(v.z), (short)f2bf(v.w) };
  *reinterpret_cast<s16x4*>(hb + i) = st;
}

// ---------------------------------------------------------------------------
// Phase A: grouped QKV projection. Tile 256x64, BK=32, 256 thr (4 waves,
// wave tile 64x64). grid (80, 16). Depth-2 reg prefetch: load k+64 while
// computing k; store k+32 between barriers.
// ---------------------------------------------------------------------------
__global__ __launch_bounds__(256, 4) void qkv_gemm(
    const unsigned short* __restrict__ hb, const float* __restrict__ Wq,
    const float* __restrict__ Wk, const float* __restrict__ Wv,
    unsigned short* __restrict__ qo, unsigned short* __restrict__ ko,
    unsigned short* __restrict__ vo)
{
  const int g    = blockIdx.y;
  const int n0   = blockIdx.x * 64;     // in 5120-wide concat
  const int tid  = threadIdx.x;
  const int lane = tid & 63;
  const int wave = tid >> 6;            // 0..3
  const int wm   = wave * 64;

  const float* W; unsigned short* out; size_t obase; int oldc, wN, c0;
  if (n0 < 512)       { W = Wq + (size_t)g * 262144;  out = qo; obase = (size_t)g * 512;  oldc = 8192;  wN = 512;  c0 = n0; }
  else if (n0 < 1024) { W = Wk + (size_t)g * 262144;  out = ko; obase = (size_t)g * 512;  oldc = 8192;  wN = 512;  c0 = n0 - 512; }
  else                { W = Wv + (size_t)g * 2097152; out = vo; obase = (size_t)g * 4096; oldc = 65536; wN = 4096; c0 = n0 - 1024; }

  const unsigned short* A = hb + (size_t)g * 512;   // rows 0..255, stride 8192

  __shared__ unsigned short As[256][40];   // [m][k] padded: bank-conflict-free b128
  __shared__ unsigned short Bs[64][36];    // [n][k] padded

  f32x4 acc[4][4];
  #pragma unroll
  for (int i = 0; i < 4; i++)
    #pragma unroll
    for (int j = 0; j < 4; j++) acc[i][j] = (f32x4){0.f, 0.f, 0.f, 0.f};

  const int fr = lane & 15, fq = lane >> 4;
  const int arow = tid >> 2, akq = tid & 3;       // A staging coords (+p*64 rows)
  const int bn = tid & 63, bkc = tid >> 6;        // B staging coords (+p*4 kc)

  // depth-2 register staging buffers (statically indexed)
  s16x8 aR0[4], aR1[4];
  f32x4 bR0[2], bR1[2];

  auto LOAD0 = [&](int k0) {
    #pragma unroll
    for (int p = 0; p < 4; p++)
      aR0[p] = *reinterpret_cast<const s16x8*>(A + (size_t)(p * 64 + arow) * 8192 + k0 + akq * 8);
    #pragma unroll
    for (int p = 0; p < 2; p++) {
      const float* wp = W + (size_t)(k0 + (p * 4 + bkc) * 4) * wN + c0 + bn;
      bR0[p] = (f32x4){ wp[0], wp[wN], wp[2 * wN], wp[3 * wN] };
    }
  };
  auto LOAD1 = [&](int k0) {
    #pragma unroll
    for (int p = 0; p < 4; p++)
      aR1[p] = *reinterpret_cast<const s16x8*>(A + (size_t)(p * 64 + arow) * 8192 + k0 + akq * 8);
    #pragma unroll
    for (int p = 0; p < 2; p++) {
      const float* wp = W + (size_t)(k0 + (p * 4 + bkc) * 4) * wN + c0 + bn;
      bR1[p] = (f32x4){ wp[0], wp[wN], wp[2 * wN], wp[3 * wN] };
    }
  };
  auto STORE0 = [&]() {
    #pragma unroll
    for (int p = 0; p < 4; p++)
      *reinterpret_cast<s16x8*>(&As[p * 64 + arow][akq * 8]) = aR0[p];
    #pragma unroll
    for (int p = 0; p < 2; p++) {
      s16x4 st = { (short)f2bf(bR0[p][0]), (short)f2bf(bR0[p][1]),
                   (short)f2bf(bR0[p][2]), (short)f2bf(bR0[p][3]) };
      *reinterpret_cast<s16x4*>(&Bs[bn][(p * 4 + bkc) * 4]) = st;
    }
  };
  auto STORE1 = [&]() {
    #pragma unroll
    for (int p = 0; p < 4; p++)
      *reinterpret_cast<s16x8*>(&As[p * 64 + arow][akq * 8]) = aR1[p];
    #pragma unroll
    for (int p = 0; p < 2; p++) {
      s16x4 st = { (short)f2bf(bR1[p][0]), (short)f2bf(bR1[p][1]),
                   (short)f2bf(bR1[p][2]), (short)f2bf(bR1[p][3]) };
      *reinterpret_cast<s16x4*>(&Bs[bn][(p * 4 + bkc) * 4]) = st;
    }
  };
  auto COMPUTE = [&]() {
    s16x8 af[4], bfr[4];
    #pragma unroll
    for (int mi = 0; mi < 4; mi++)
      af[mi] = *reinterpret_cast<const s16x8*>(&As[wm + mi * 16 + fr][fq * 8]);
    #pragma unroll
    for (int ni = 0; ni < 4; ni++) {
      const s16x4* bp = reinterpret_cast<const s16x4*>(&Bs[ni * 16 + fr][fq * 8]);
      s16x4 lo = bp[0], hi = bp[1];
      bfr[ni] = __builtin_shufflevector(lo, hi, 0, 1, 2, 3, 4, 5, 6, 7);
    }
    #pragma unroll
    for (int mi = 0; mi < 4; mi++)
      #pragma unroll
      for (int ni = 0; ni < 4; ni++)
        acc[mi][ni] = __builtin_amdgcn_mfma_f32_16x16x32_bf16(af[mi], bfr[ni], acc[mi][ni], 0, 0, 0);
  };

  // prologue: R0 <- tile 0, R1 <- tile 32, LDS <- tile 0
  LOAD0(0);
  LOAD1(32);
  STORE0();
  __syncthreads();

  // 8 double-steps over K=512
  for (int k0 = 0; k0 < 512; k0 += 64) {
    // even: compute k0; prefetch k0+64 -> R0; publish k0+32 (R1)
    if (k0 + 64 < 512) LOAD0(k0 + 64);
    COMPUTE();
    __syncthreads();
    STORE1();                       // k0+32 always exists (k0 <= 448)
    __syncthreads();
    // odd: compute k0+32; prefetch k0+96 -> R1; publish k0+64 (R0)
    if (k0 + 96 < 512) LOAD1(k0 + 96);
    COMPUTE();
    if (k0 + 64 < 512) {
      __syncthreads();
      STORE0();
      __syncthreads();
    }
  }

  #pragma unroll
  for (int mi = 0; mi < 4; mi++)
    #pragma unroll
    for (int ni = 0; ni < 4; ni++)
      #pragma unroll
      for (int r = 0; r < 4; r++) {
        int row = wm + mi * 16 + fq * 4 + r;
        int col = c0 + ni * 16 + fr;
        out[obase + (size_t)row * oldc + col] = f2bf(acc[mi][ni][r]);
      }
}

// ---------------------------------------------------------------------------
// Phase B: per-(b,h) attention, vectorized. grid 2048, block 256.
// ---------------------------------------------------------------------------
__global__ __launch_bounds__(256) void attn_kernel(
    const unsigned short* __restrict__ q, const unsigned short* __restrict__ k,
    const unsigned short* __restrict__ v, const int* __restrict__ mask,
    unsigned short* __restrict__ ctx)
{
  const int b  = blockIdx.x >> 3;
  const int hh = blockIdx.x & 7;
  const int tid = threadIdx.x;

  __shared__ float qs[16][65];
  __shared__ float ks[16][65];
  __shared__ float sc[16][16];

  {
    int n = tid >> 4, d4 = (tid & 15) * 4;
    size_t gi = ((size_t)(b * 16 + n) << 9) + (hh << 6) + d4;
    ushort4 qv = *reinterpret_cast<const ushort4*>(q + gi);
    ushort4 kv = *reinterpret_cast<const ushort4*>(k + gi);
    qs[n][d4] = bf2f(qv.x); qs[n][d4+1] = bf2f(qv.y); qs[n][d4+2] = bf2f(qv.z); qs[n][d4+3] = bf2f(qv.w);
    ks[n][d4] = bf2f(kv.x); ks[n][d4+1] = bf2f(kv.y); ks[n][d4+2] = bf2f(kv.z); ks[n][d4+3] = bf2f(kv.w);
  }
  __syncthreads();
  {
    int qi = tid >> 4, ki = tid & 15;
    float s = 0.f;
    #pragma unroll
    for (int j = 0; j < 64; j++) s += qs[qi][j] * ks[ki][j];
    sc[qi][ki] = s * 0.125f;   // 1/sqrt(64)
  }
  __syncthreads();
  if (tid < 16) {
    float m = sc[tid][0];
    #pragma unroll
    for (int j = 1; j < 16; j++) m = fmaxf(m, sc[tid][j]);
    float ev[16], sum = 0.f;
    #pragma unroll
    for (int j = 0; j < 16; j++) { ev[j] = __expf(sc[tid][j] - m); sum += ev[j]; }
    float scale = (mask[b * 16 + tid] != 0) ? (1.f / sum) : 0.f;
    #pragma unroll
    for (int j = 0; j < 16; j++) sc[tid][j] = ev[j] * scale;
  }
  __syncthreads();
  // PV: thread owns 4 cols x 8 queries. v rows read as ushort4.
  {
    int col4  = (tid & 127) * 4;
    int qbase = (tid >> 7) * 8;
    float a0[8], a1[8], a2[8], a3[8];
    #pragma unroll
    for (int j = 0; j < 8; j++) { a0[j] = 0.f; a1[j] = 0.f; a2[j] = 0.f; a3[j] = 0.f; }
    #pragma unroll
    for (int kk = 0; kk < 16; kk++) {
      ushort4 vv = *reinterpret_cast<const ushort4*>(
          v + ((size_t)(b * 16 + kk) << 12) + (hh << 9) + col4);
      float v0 = bf2f(vv.x), v1 = bf2f(vv.y), v2 = bf2f(vv.z), v3 = bf2f(vv.w);
      #pragma unroll
      for (int j = 0; j < 8; j++) {
        float p = sc[qbase + j][kk];
        a0[j] += p * v0; a1[j] += p * v1; a2[j] += p * v2; a3[j] += p * v3;
      }
    }
    #pragma unroll
    for (int j = 0; j < 8; j++) {
      ushort4 st = { f2bf(a0[j]), f2bf(a1[j]), f2bf(a2[j]), f2bf(a3[j]) };
      *reinterpret_cast<ushort4*>(
          ctx + ((size_t)(b * 16 + qbase + j) << 12) + (hh << 9) + col4) = st;
    }
  }
}

// ---------------------------------------------------------------------------
// Phase C: partial[sk] = ctx @ Wo[g] over K-slice. Tile 256x64, 512 thr
// (8 waves, wave tile 64x32), split-K=4. grid (32, 16): bx = sk*8 + nb.
// Depth-2 reg prefetch identical to qkv_gemm.
// ---------------------------------------------------------------------------
__global__ __launch_bounds__(512, 4) void out_gemm(
    const unsigned short* __restrict__ ctxp, const float* __restrict__ Wo,
    float* __restrict__ partial)
{
  const int g    = blockIdx.y;
  const int bx   = blockIdx.x;
  const int sk   = bx >> 3;             // 0..3
  const int n0   = (bx & 7) * 64;       // 0..448
  const int tid  = threadIdx.x;
  const int lane = tid & 63;
  const int wave = tid >> 6;            // 0..7
  const int wm   = (wave >> 1) * 64;    // 4 positions
  const int wn   = (wave & 1) * 32;     // 2 positions

  const unsigned short* A = ctxp + (size_t)g * 4096;  // rows 0..255, stride 65536
  const float* W = Wo + (size_t)g * 2097152;          // 4096 x 512 fp32

  __shared__ unsigned short As[256][40];
  __shared__ unsigned short Bs[64][36];

  f32x4 acc[4][2];
  #pragma unroll
  for (int i = 0; i < 4; i++)
    #pragma unroll
    for (int j = 0; j < 2; j++) acc[i][j] = (f32x4){0.f, 0.f, 0.f, 0.f};

  const int fr = lane & 15, fq = lane >> 4;
  const int arow = tid >> 2, akq = tid & 3;   // A: +p*128 rows
  const int bn = tid & 63, bkc = tid >> 6;    // B: kc 0..7

  s16x8 aR0[2], aR1[2];
  f32x4 bR0, bR1;

  auto LOAD0 = [&](int k0) {
    #pragma unroll
    for (int p = 0; p < 2; p++)
      aR0[p] = *reinterpret_cast<const s16x8*>(A + (size_t)(p * 128 + arow) * 65536 + k0 + akq * 8);
    const float* wp = W + (size_t)(k0 + bkc * 4) * 512 + n0 + bn;
    bR0 = (f32x4){ wp[0], wp[512], wp[1024], wp[1536] };
  };
  auto LOAD1 = [&](int k0) {
    #pragma unroll
    for (int p = 0; p < 2; p++)
      aR1[p] = *reinterpret_cast<const s16x8*>(A + (size_t)(p * 128 + arow) * 65536 + k0 + akq * 8);
    const float* wp = W + (size_t)(k0 + bkc * 4) * 512 + n0 + bn;
    bR1 = (f32x4){ wp[0], wp[512], wp[1024], wp[1536] };
  };
  auto STORE0 = [&]() {
    #pragma unroll
    for (int p = 0; p < 2; p++)
      *reinterpret_cast<s16x8*>(&As[p * 128 + arow][akq * 8]) = aR0[p];
    s16x4 st = { (short)f2bf(bR0[0]), (short)f2bf(bR0[1]),
                 (short)f2bf(bR0[2]), (short)f2bf(bR0[3]) };
    *reinterpret_cast<s16x4*>(&Bs[bn][bkc * 4]) = st;
  };
  auto STORE1 = [&]() {
    #pragma unroll
    for (int p = 0; p < 2; p++)
      *reinterpret_cast<s16x8*>(&As[p * 128 + arow][akq * 8]) = aR1[p];
    s16x4 st = { (short)f2bf(bR1[0]), (short)f2bf(bR1[1]),
                 (short)f2bf(bR1[2]), (short)f2bf(bR1[3]) };
    *reinterpret_cast<s16x4*>(&Bs[bn][bkc * 4]) = st;
  };
  auto COMPUTE = [&]() {
    s16x8 af[4], bfr[2];
    #pragma unroll
    for (int mi = 0; mi < 4; mi++)
      af[mi] = *reinterpret_cast<const s16x8*>(&As[wm + mi * 16 + fr][fq * 8]);
    #pragma unroll
    for (int ni = 0; ni < 2; ni++) {
      const s16x4* bp = reinterpret_cast<const s16x4*>(&Bs[wn + ni * 16 + fr][fq * 8]);
      s16x4 lo = bp[0], hi = bp[1];
      bfr[ni] = __builtin_shufflevector(lo, hi, 0, 1, 2, 3, 4, 5, 6, 7);
    }
    #pragma unroll
    for (int mi = 0; mi < 4; mi++)
      #pragma unroll
      for (int ni = 0; ni < 2; ni++)
        acc[mi][ni] = __builtin_amdgcn_mfma_f32_16x16x32_bf16(af[mi], bfr[ni], acc[mi][ni], 0, 0, 0);
  };

  const int ks = sk * 1024, kend = ks + 1024;

  LOAD0(ks);
  LOAD1(ks + 32);
  STORE0();
  __syncthreads();

  for (int k0 = ks; k0 < kend; k0 += 64) {
    if (k0 + 64 < kend) LOAD0(k0 + 64);
    COMPUTE();
    __syncthreads();
    STORE1();
    __syncthreads();
    if (k0 + 96 < kend) LOAD1(k0 + 96);
    COMPUTE();
    if (k0 + 64 < kend) {
      __syncthreads();
      STORE0();
      __syncthreads();
    }
  }

  float* pg = partial + (size_t)sk * 2097152 + (size_t)g * 512;
  #pragma unroll
  for (int mi = 0; mi < 4; mi++)
    #pragma unroll
    for (int ni = 0; ni < 2; ni++)
      #pragma unroll
      for (int r = 0; r < 4; r++) {
        int row = wm + mi * 16 + fq * 4 + r;
        int col = n0 + wn + ni * 16 + fr;
        pg[(size_t)row * 8192 + col] = acc[mi][ni][r];
      }
}

// ---------------------------------------------------------------------------
// Epilogue: out = sum of 4 split-K partials. grid 2048 x 256.
// ---------------------------------------------------------------------------
__global__ __launch_bounds__(256) void reduce4(const float* __restrict__ part,
                                               float* __restrict__ out)
{
  int i = (blockIdx.x * 256 + threadIdx.x) * 4;
  float4 a = *reinterpret_cast<const float4*>(part + i);
  float4 b = *reinterpret_cast<const float4*>(part + 2097152 + i);
  float4 c = *reinterpret_cast<const float4*>(part + 4194304 + i);
  float4 d = *reinterpret_cast<const float4*>(part + 6291456 + i);
  float4 s = { a.x + b.x + c.x + d.x, a.y + b.y + c.y + d.y,
               a.z + b.z + c.z + d.z, a.w + b.w + c.w + d.w };
  *reinterpret_cast<float4*>(out + i) = s;
}

// ---------------------------------------------------------------------------
extern "C" void kernel_launch(void* const* d_in, const int* in_sizes, int n_in,
                              void* d_out, int out_size, void* d_ws, size_t ws_size,
                              hipStream_t stream) {
  const float* h  = (const float*)d_in[0];
  const int* mask = (const int*)d_in[1];
  const float* Wk = (const float*)d_in[2];   // dict order: Wk before Wq
  const float* Wq = (const float*)d_in[3];
  const float* Wv = (const float*)d_in[4];
  const float* Wo = (const float*)d_in[5];
  float* out = (float*)d_out;

  // ws layout: q(4MB) | k(4MB) | v(33.5MB) | ctx(33.5MB)
  // hb (4MB)  aliases ctx region   (dead once attn writes ctx)
  // partials (33.5MB) alias q/k/v  (dead once out_gemm runs)
  unsigned short* qws   = (unsigned short*)d_ws;
  unsigned short* kws   = qws + 2097152;
  unsigned short* vws   = kws + 2097152;
  unsigned short* ctxws = vws + 16777216;
  unsigned short* hb    = ctxws;             // alias: used before attn only
  float* part           = (float*)d_ws;      // alias: used after attn only

  cvt_h<<<2048, 256, 0, stream>>>(h, hb);
  qkv_gemm<<<dim3(80, 16), 256, 0, stream>>>(hb, Wq, Wk, Wv, qws, kws, vws);
  attn_kernel<<<2048, 256, 0, stream>>>(qws, kws, vws, mask, ctxws);
  out_gemm<<<dim3(32, 16), 512, 0, stream>>>(ctxws, Wo, part);
  reduce4<<<2048, 256, 0, stream>>>(part, out);
}

// Round 2
// 387.449 us; speedup vs baseline: 1.7357x; 1.7357x over previous
//
#include <hip/hip_runtime.h>

// CommAttention: B=256, NB=16, HID=512, NH=8, KD=64.
// R4: R2 skeleton + depth-1 register prefetch (single reg buffer, issued
// before COMPUTE, consumed by STORE next iter) + As padded [256][40] to
// kill the 8-way bank conflict on b128 A-fragment reads. NO launch_bounds
// register cap (R3's cap + depth-2 buffers spilled to scratch: WRITE_SIZE
// 41->670 MB). Attn / cvt / reduce unchanged.

typedef short s16x4 __attribute__((ext_vector_type(4)));
typedef short s16x8 __attribute__((ext_vector_type(8)));
typedef float f32x4 __attribute__((ext_vector_type(4)));

__device__ __forceinline__ unsigned short f2bf(float f) {
  unsigned int u = __builtin_bit_cast(unsigned int, f);
  u += 0x7fffu + ((u >> 16) & 1u);   // round-to-nearest-even
  return (unsigned short)(u >> 16);
}
__device__ __forceinline__ float bf2f(unsigned short s) {
  unsigned int u = ((unsigned int)s) << 16;
  return __builtin_bit_cast(float, u);
}

// ---------------------------------------------------------------------------
// Prologue: h (2M fp32) -> bf16. grid 2048 x 256.
// ---------------------------------------------------------------------------
__global__ __launch_bounds__(256) void cvt_h(const float* __restrict__ h,
                                             unsigned short* __restrict__ hb)
{
  int i = (blockIdx.x * 256 + threadIdx.x) * 4;
  float4 v = *reinterpret_cast<const float4*>(h + i);
  s16x4 st = { (short)f2bf(v.x), (short)f2bf(v.y), (short)f2bf(v.z), (short)f2bf(v.w) };
  *reinterpret_cast<s16x4*>(hb + i) = st;
}

// ---------------------------------------------------------------------------
// Phase A: grouped QKV projection. Tile 256x64, BK=32, 256 thr (4 waves,
// wave tile 64x64). grid (80, 16). Depth-1 reg prefetch: LOAD(k+32) issued
// between barrier and COMPUTE(k); consumed by STORE at top of next iter.
// ---------------------------------------------------------------------------
__global__ __launch_bounds__(256) void qkv_gemm(
    const unsigned short* __restrict__ hb, const float* __restrict__ Wq,
    const float* __restrict__ Wk, const float* __restrict__ Wv,
    unsigned short* __restrict__ qo, unsigned short* __restrict__ ko,
    unsigned short* __restrict__ vo)
{
  const int g    = blockIdx.y;
  const int n0   = blockIdx.x * 64;     // in 5120-wide concat
  const int tid  = threadIdx.x;
  const int lane = tid & 63;
  const int wave = tid >> 6;            // 0..3
  const int wm   = wave * 64;

  const float* W; unsigned short* out; size_t obase; int oldc, wN, c0;
  if (n0 < 512)       { W = Wq + (size_t)g * 262144;  out = qo; obase = (size_t)g * 512;  oldc = 8192;  wN = 512;  c0 = n0; }
  else if (n0 < 1024) { W = Wk + (size_t)g * 262144;  out = ko; obase = (size_t)g * 512;  oldc = 8192;  wN = 512;  c0 = n0 - 512; }
  else                { W = Wv + (size_t)g * 2097152; out = vo; obase = (size_t)g * 4096; oldc = 65536; wN = 4096; c0 = n0 - 1024; }

  const unsigned short* A = hb + (size_t)g * 512;   // rows 0..255, stride 8192

  __shared__ unsigned short As[256][40];   // padded: 80B rows -> ~2-way banks on b128
  __shared__ unsigned short Bs[64][36];    // [n][k] padded

  f32x4 acc[4][4];
  #pragma unroll
  for (int i = 0; i < 4; i++)
    #pragma unroll
    for (int j = 0; j < 4; j++) acc[i][j] = (f32x4){0.f, 0.f, 0.f, 0.f};

  const int fr = lane & 15, fq = lane >> 4;
  const int arow = tid >> 2, akq = tid & 3;       // A staging (+p*64 rows)
  const int bn = tid & 63, bkc = tid >> 6;        // B staging (+p*4 kc)

  // depth-1 register staging buffer (statically indexed)
  s16x8 aR[4];
  f32x4 bR[2];

  auto LOAD = [&](int k0) {
    #pragma unroll
    for (int p = 0; p < 4; p++)
      aR[p] = *reinterpret_cast<const s16x8*>(A + (size_t)(p * 64 + arow) * 8192 + k0 + akq * 8);
    #pragma unroll
    for (int p = 0; p < 2; p++) {
      const float* wp = W + (size_t)(k0 + (p * 4 + bkc) * 4) * wN + c0 + bn;
      bR[p] = (f32x4){ wp[0], wp[wN], wp[2 * wN], wp[3 * wN] };
    }
  };
  auto STORE = [&]() {
    #pragma unroll
    for (int p = 0; p < 4; p++)
      *reinterpret_cast<s16x8*>(&As[p * 64 + arow][akq * 8]) = aR[p];
    #pragma unroll
    for (int p = 0; p < 2; p++) {
      s16x4 st = { (short)f2bf(bR[p][0]), (short)f2bf(bR[p][1]),
                   (short)f2bf(bR[p][2]), (short)f2bf(bR[p][3]) };
      *reinterpret_cast<s16x4*>(&Bs[bn][(p * 4 + bkc) * 4]) = st;
    }
  };
  auto COMPUTE = [&]() {
    s16x8 af[4], bfr[4];
    #pragma unroll
    for (int mi = 0; mi < 4; mi++)
      af[mi] = *reinterpret_cast<const s16x8*>(&As[wm + mi * 16 + fr][fq * 8]);
    #pragma unroll
    for (int ni = 0; ni < 4; ni++) {
      const s16x4* bp = reinterpret_cast<const s16x4*>(&Bs[ni * 16 + fr][fq * 8]);
      s16x4 lo = bp[0], hi = bp[1];
      bfr[ni] = __builtin_shufflevector(lo, hi, 0, 1, 2, 3, 4, 5, 6, 7);
    }
    #pragma unroll
    for (int mi = 0; mi < 4; mi++)
      #pragma unroll
      for (int ni = 0; ni < 4; ni++)
        acc[mi][ni] = __builtin_amdgcn_mfma_f32_16x16x32_bf16(af[mi], bfr[ni], acc[mi][ni], 0, 0, 0);
  };

  LOAD(0);
  for (int k0 = 0; k0 < 512; k0 += 32) {
    __syncthreads();                 // previous COMPUTE done -> LDS reusable
    STORE();                         // publish tile k0 (waits on its loads)
    __syncthreads();
    if (k0 + 32 < 512) LOAD(k0 + 32);  // issue next tile; lands during COMPUTE
    COMPUTE();
  }

  #pragma unroll
  for (int mi = 0; mi < 4; mi++)
    #pragma unroll
    for (int ni = 0; ni < 4; ni++)
      #pragma unroll
      for (int r = 0; r < 4; r++) {
        int row = wm + mi * 16 + fq * 4 + r;
        int col = c0 + ni * 16 + fr;
        out[obase + (size_t)row * oldc + col] = f2bf(acc[mi][ni][r]);
      }
}

// ---------------------------------------------------------------------------
// Phase B: per-(b,h) attention, vectorized. grid 2048, block 256.
// ---------------------------------------------------------------------------
__global__ __launch_bounds__(256) void attn_kernel(
    const unsigned short* __restrict__ q, const unsigned short* __restrict__ k,
    const unsigned short* __restrict__ v, const int* __restrict__ mask,
    unsigned short* __restrict__ ctx)
{
  const int b  = blockIdx.x >> 3;
  const int hh = blockIdx.x & 7;
  const int tid = threadIdx.x;

  __shared__ float qs[16][65];
  __shared__ float ks[16][65];
  __shared__ float sc[16][16];

  {
    int n = tid >> 4, d4 = (tid & 15) * 4;
    size_t gi = ((size_t)(b * 16 + n) << 9) + (hh << 6) + d4;
    ushort4 qv = *reinterpret_cast<const ushort4*>(q + gi);
    ushort4 kv = *reinterpret_cast<const ushort4*>(k + gi);
    qs[n][d4] = bf2f(qv.x); qs[n][d4+1] = bf2f(qv.y); qs[n][d4+2] = bf2f(qv.z); qs[n][d4+3] = bf2f(qv.w);
    ks[n][d4] = bf2f(kv.x); ks[n][d4+1] = bf2f(kv.y); ks[n][d4+2] = bf2f(kv.z); ks[n][d4+3] = bf2f(kv.w);
  }
  __syncthreads();
  {
    int qi = tid >> 4, ki = tid & 15;
    float s = 0.f;
    #pragma unroll
    for (int j = 0; j < 64; j++) s += qs[qi][j] * ks[ki][j];
    sc[qi][ki] = s * 0.125f;   // 1/sqrt(64)
  }
  __syncthreads();
  if (tid < 16) {
    float m = sc[tid][0];
    #pragma unroll
    for (int j = 1; j < 16; j++) m = fmaxf(m, sc[tid][j]);
    float ev[16], sum = 0.f;
    #pragma unroll
    for (int j = 0; j < 16; j++) { ev[j] = __expf(sc[tid][j] - m); sum += ev[j]; }
    float scale = (mask[b * 16 + tid] != 0) ? (1.f / sum) : 0.f;
    #pragma unroll
    for (int j = 0; j < 16; j++) sc[tid][j] = ev[j] * scale;
  }
  __syncthreads();
  // PV: thread owns 4 cols x 8 queries. v rows read as ushort4.
  {
    int col4  = (tid & 127) * 4;
    int qbase = (tid >> 7) * 8;
    float a0[8], a1[8], a2[8], a3[8];
    #pragma unroll
    for (int j = 0; j < 8; j++) { a0[j] = 0.f; a1[j] = 0.f; a2[j] = 0.f; a3[j] = 0.f; }
    #pragma unroll
    for (int kk = 0; kk < 16; kk++) {
      ushort4 vv = *reinterpret_cast<const ushort4*>(
          v + ((size_t)(b * 16 + kk) << 12) + (hh << 9) + col4);
      float v0 = bf2f(vv.x), v1 = bf2f(vv.y), v2 = bf2f(vv.z), v3 = bf2f(vv.w);
      #pragma unroll
      for (int j = 0; j < 8; j++) {
        float p = sc[qbase + j][kk];
        a0[j] += p * v0; a1[j] += p * v1; a2[j] += p * v2; a3[j] += p * v3;
      }
    }
    #pragma unroll
    for (int j = 0; j < 8; j++) {
      ushort4 st = { f2bf(a0[j]), f2bf(a1[j]), f2bf(a2[j]), f2bf(a3[j]) };
      *reinterpret_cast<ushort4*>(
          ctx + ((size_t)(b * 16 + qbase + j) << 12) + (hh << 9) + col4) = st;
    }
  }
}

// ---------------------------------------------------------------------------
// Phase C: partial[sk] = ctx @ Wo[g] over K-slice. Tile 256x64, 512 thr
// (8 waves, wave tile 64x32), split-K=4. grid (32, 16). Depth-1 reg
// prefetch identical to qkv_gemm.
// ---------------------------------------------------------------------------
__global__ __launch_bounds__(512) void out_gemm(
    const unsigned short* __restrict__ ctxp, const float* __restrict__ Wo,
    float* __restrict__ partial)
{
  const int g    = blockIdx.y;
  const int bx   = blockIdx.x;
  const int sk   = bx >> 3;             // 0..3
  const int n0   = (bx & 7) * 64;       // 0..448
  const int tid  = threadIdx.x;
  const int lane = tid & 63;
  const int wave = tid >> 6;            // 0..7
  const int wm   = (wave >> 1) * 64;    // 4 positions
  const int wn   = (wave & 1) * 32;     // 2 positions

  const unsigned short* A = ctxp + (size_t)g * 4096;  // rows 0..255, stride 65536
  const float* W = Wo + (size_t)g * 2097152;          // 4096 x 512 fp32

  __shared__ unsigned short As[256][40];
  __shared__ unsigned short Bs[64][36];

  f32x4 acc[4][2];
  #pragma unroll
  for (int i = 0; i < 4; i++)
    #pragma unroll
    for (int j = 0; j < 2; j++) acc[i][j] = (f32x4){0.f, 0.f, 0.f, 0.f};

  const int fr = lane & 15, fq = lane >> 4;
  const int arow = tid >> 2, akq = tid & 3;   // A: +p*128 rows
  const int bn = tid & 63, bkc = tid >> 6;    // B: kc 0..7

  s16x8 aR[2];
  f32x4 bR;

  auto LOAD = [&](int k0) {
    #pragma unroll
    for (int p = 0; p < 2; p++)
      aR[p] = *reinterpret_cast<const s16x8*>(A + (size_t)(p * 128 + arow) * 65536 + k0 + akq * 8);
    const float* wp = W + (size_t)(k0 + bkc * 4) * 512 + n0 + bn;
    bR = (f32x4){ wp[0], wp[512], wp[1024], wp[1536] };
  };
  auto STORE = [&]() {
    #pragma unroll
    for (int p = 0; p < 2; p++)
      *reinterpret_cast<s16x8*>(&As[p * 128 + arow][akq * 8]) = aR[p];
    s16x4 st = { (short)f2bf(bR[0]), (short)f2bf(bR[1]),
                 (short)f2bf(bR[2]), (short)f2bf(bR[3]) };
    *reinterpret_cast<s16x4*>(&Bs[bn][bkc * 4]) = st;
  };
  auto COMPUTE = [&]() {
    s16x8 af[4], bfr[2];
    #pragma unroll
    for (int mi = 0; mi < 4; mi++)
      af[mi] = *reinterpret_cast<const s16x8*>(&As[wm + mi * 16 + fr][fq * 8]);
    #pragma unroll
    for (int ni = 0; ni < 2; ni++) {
      const s16x4* bp = reinterpret_cast<const s16x4*>(&Bs[wn + ni * 16 + fr][fq * 8]);
      s16x4 lo = bp[0], hi = bp[1];
      bfr[ni] = __builtin_shufflevector(lo, hi, 0, 1, 2, 3, 4, 5, 6, 7);
    }
    #pragma unroll
    for (int mi = 0; mi < 4; mi++)
      #pragma unroll
      for (int ni = 0; ni < 2; ni++)
        acc[mi][ni] = __builtin_amdgcn_mfma_f32_16x16x32_bf16(af[mi], bfr[ni], acc[mi][ni], 0, 0, 0);
  };

  const int ks = sk * 1024, kend = ks + 1024;

  LOAD(ks);
  for (int k0 = ks; k0 < kend; k0 += 32) {
    __syncthreads();
    STORE();
    __syncthreads();
    if (k0 + 32 < kend) LOAD(k0 + 32);
    COMPUTE();
  }

  float* pg = partial + (size_t)sk * 2097152 + (size_t)g * 512;
  #pragma unroll
  for (int mi = 0; mi < 4; mi++)
    #pragma unroll
    for (int ni = 0; ni < 2; ni++)
      #pragma unroll
      for (int r = 0; r < 4; r++) {
        int row = wm + mi * 16 + fq * 4 + r;
        int col = n0 + wn + ni * 16 + fr;
        pg[(size_t)row * 8192 + col] = acc[mi][ni][r];
      }
}

// ---------------------------------------------------------------------------
// Epilogue: out = sum of 4 split-K partials. grid 2048 x 256.
// ---------------------------------------------------------------------------
__global__ __launch_bounds__(256) void reduce4(const float* __restrict__ part,
                                               float* __restrict__ out)
{
  int i = (blockIdx.x * 256 + threadIdx.x) * 4;
  float4 a = *reinterpret_cast<const float4*>(part + i);
  float4 b = *reinterpret_cast<const float4*>(part + 2097152 + i);
  float4 c = *reinterpret_cast<const float4*>(part + 4194304 + i);
  float4 d = *reinterpret_cast<const float4*>(part + 6291456 + i);
  float4 s = { a.x + b.x + c.x + d.x, a.y + b.y + c.y + d.y,
               a.z + b.z + c.z + d.z, a.w + b.w + c.w + d.w };
  *reinterpret_cast<float4*>(out + i) = s;
}

// ---------------------------------------------------------------------------
extern "C" void kernel_launch(void* const* d_in, const int* in_sizes, int n_in,
                              void* d_out, int out_size, void* d_ws, size_t ws_size,
                              hipStream_t stream) {
  const float* h  = (const float*)d_in[0];
  const int* mask = (const int*)d_in[1];
  const float* Wk = (const float*)d_in[2];   // dict order: Wk before Wq
  const float* Wq = (const float*)d_in[3];
  const float* Wv = (const float*)d_in[4];
  const float* Wo = (const float*)d_in[5];
  float* out = (float*)d_out;

  // ws layout: q(4MB) | k(4MB) | v(33.5MB) | ctx(33.5MB)
  // hb (4MB)  aliases ctx region   (dead once attn writes ctx)
  // partials (33.5MB) alias q/k/v  (dead once out_gemm runs)
  unsigned short* qws   = (unsigned short*)d_ws;
  unsigned short* kws   = qws + 2097152;
  unsigned short* vws   = kws + 2097152;
  unsigned short* ctxws = vws + 16777216;
  unsigned short* hb    = ctxws;             // alias: used before attn only
  float* part           = (float*)d_ws;      // alias: used after attn only

  cvt_h<<<2048, 256, 0, stream>>>(h, hb);
  qkv_gemm<<<dim3(80, 16), 256, 0, stream>>>(hb, Wq, Wk, Wv, qws, kws, vws);
  attn_kernel<<<2048, 256, 0, stream>>>(qws, kws, vws, mask, ctxws);
  out_gemm<<<dim3(32, 16), 512, 0, stream>>>(ctxws, Wo, part);
  reduce4<<<2048, 256, 0, stream>>>(part, out);
}